// Round 21
// baseline (499.655 us; speedup 1.0000x reference)
//
#include <hip/hip_runtime.h>
#include <stdint.h>

// TopKRouter: T=32768, D=1024, E=64, k=2 (device scalar), C=1280 (from out_size).
//
// Correctness model (VERIFIED PASSING r19/r20): np golden = numpy f32
// transliteration.
// logits = x @ W.T + b, K panels [0,512)[512,1024): single-accumulator
//   ascending-k f32 FMA chain per panel, panels summed left-to-right, + b.
// softmax f32: AVX512 FLOAT_exp (Cephes, FMA, rint, scalef); SSE npyv 4-lane
//   pairwise sum + SSE3 hadd horizontal; CR divide; exact max-subtract.
// top-k & capacity sort on f32 probs, ties -> lower index (stable).
// expert_indices stored as f32 values (-1.0f padding).
//
// r21 perf changes (bit-exact preserving):
//  - GEMM: W-tile staged in LDS (WS 16KB/tile) -> inner loop is pure-LDS
//    (1 varying b32 + 2 uniform b128 per k-step). r20 was latency-bound on
//    2 global dwordx4/k-step (VALUBusy 14%, VGPR 56 = no prefetch headroom).
//  - Sort: kernel B appends slots into per-expert buckets via atomicAdd
//    (keys unique -> deterministic sorted output); kernel C skips the
//    64x65536 gather scan. cnt zeroed per-launch by a tiny kernel.

#define THREADS 256
#define KMAX 16
#define BUCKET 4096

// ---- numpy AVX512 FLOAT_exp replica: Cephes constants, FMA, rint quadrant ---
__device__ __forceinline__ float np_expf_avx512(float x)
{
    const float log2e = 1.442695040888963f;      // NPY_LOG2Ef
    float t = x * log2e;                          // separate mul (vmulps)
    float q = rintf(t);                           // roundscale nearest-even
    float r = fmaf(q, -0.693359375f, x);          // Cody-Waite hi (fma)
    r = fmaf(q, 2.12194440e-4f, r);               // Cody-Waite lo (fma)
    float y = 1.9875691500E-4f;                   // cephes_exp_p0..p5
    y = fmaf(y, r, 1.3981999507E-3f);
    y = fmaf(y, r, 8.3334519073E-3f);
    y = fmaf(y, r, 4.1665795894E-2f);
    y = fmaf(y, r, 1.6666665459E-1f);
    y = fmaf(y, r, 5.0000001201E-1f);
    float rr = r * r;                             // separate mul
    y = fmaf(y, rr, r);                           // poly*r^2 + r
    y = y + 1.0f;
    return ldexpf(y, (int)q);                     // vscalefps (q integral)
}

// ---------------- Kernel T: transpose W (E x D) -> WT (D x E, k-major) -------
__global__ __launch_bounds__(256)
void transpose_w_kernel(const float* __restrict__ W, float* __restrict__ WT,
                        int D, int E)
{
    const int e = blockIdx.x;
    for (int k = threadIdx.x; k < D; k += 256)
        WT[(size_t)k * E + e] = W[(size_t)e * D + k];
}

// ---------------- Kernel Z: zero per-expert counters -------------------------
__global__ void zero_cnt_kernel(int* __restrict__ cnt, int E)
{
    if (threadIdx.x < E) cnt[threadIdx.x] = 0;
}

// ---------------- Kernel A: f32 logits, 512/512 K-panel FMA chains -----------
// Grid: T/64 blocks x 512 thr (8 waves). lane = token (64/block);
// wave w handles experts [8w, 8w+8). Per thread: acc[8] f32 chains.
// x staged transposed in LDS XT (stride 65); W-tile staged in LDS WS.
#define KC 64
__global__ __launch_bounds__(512, 4)
void gemm_f32_kernel(const float* __restrict__ x, const float* __restrict__ WT,
                     const float* __restrict__ bias,
                     float* __restrict__ logits_out, int T, int D, int E)
{
    const int tid  = threadIdx.x;
    const int lane = tid & 63;
    const int w    = tid >> 6;            // 0..7: expert octet
    const int tok0 = blockIdx.x * 64;

    __shared__ float XT[64 * 65];         // XT[k][t] stride 65; reused as LT
    __shared__ float WS[64 * 64];         // WS[k][e] contiguous

    float acc[8], ztot[8];
#pragma unroll
    for (int j = 0; j < 8; ++j) { acc[j] = 0.0f; ztot[j] = 0.0f; }

    const int cc = tid & 15;              // float4 index within a 64-float row
    const int r0 = tid >> 4;              // 0..31

    for (int kc = 0; kc < 1024; kc += KC) {
        __syncthreads();
        // stage XT[k][t] = x[tok0+t][kc+k]   (512 threads, 2 rows each)
        for (int r = r0; r < 64; r += 32) {
            float4 v = *reinterpret_cast<const float4*>(
                x + (size_t)(tok0 + r) * D + kc + 4 * cc);
            XT[(4 * cc + 0) * 65 + r] = v.x;
            XT[(4 * cc + 1) * 65 + r] = v.y;
            XT[(4 * cc + 2) * 65 + r] = v.z;
            XT[(4 * cc + 3) * 65 + r] = v.w;
        }
        // stage WS = WT[kc..kc+64)[0..64): 16KB contiguous, 2 float4/thread
        {
            const float4* src = reinterpret_cast<const float4*>(
                WT + (size_t)kc * 64);
            float4* dst = reinterpret_cast<float4*>(WS);
            dst[tid]       = src[tid];
            dst[tid + 512] = src[tid + 512];
        }
        __syncthreads();

#pragma unroll 8
        for (int k = 0; k < KC; ++k) {
            float xv = XT[k * 65 + lane];
            const float* wrow = WS + k * 64 + w * 8;   // wave-uniform
            float4 wv0 = *reinterpret_cast<const float4*>(wrow);
            float4 wv1 = *reinterpret_cast<const float4*>(wrow + 4);
            acc[0] = fmaf(xv, wv0.x, acc[0]);
            acc[1] = fmaf(xv, wv0.y, acc[1]);
            acc[2] = fmaf(xv, wv0.z, acc[2]);
            acc[3] = fmaf(xv, wv0.w, acc[3]);
            acc[4] = fmaf(xv, wv1.x, acc[4]);
            acc[5] = fmaf(xv, wv1.y, acc[5]);
            acc[6] = fmaf(xv, wv1.z, acc[6]);
            acc[7] = fmaf(xv, wv1.w, acc[7]);
        }
        // K panels 512/512: fold at tile boundaries only (bit-exact)
        int kend = kc + KC;
        if (kend == 512 || kend == 1024) {
#pragma unroll
            for (int j = 0; j < 8; ++j) { ztot[j] += acc[j]; acc[j] = 0.0f; }
        }
    }

#pragma unroll
    for (int j = 0; j < 8; ++j) ztot[j] += bias[w * 8 + j];

    // transpose via LDS (reuse XT as LT[t][e], stride 65), coalesced store
    __syncthreads();
#pragma unroll
    for (int j = 0; j < 8; ++j) XT[lane * 65 + w * 8 + j] = ztot[j];
    __syncthreads();
    for (int it = 0; it < 8; ++it) {
        int i = it * 512 + tid;           // 0..4095
        int t = i >> 6, e = i & 63;
        logits_out[(size_t)(tok0 + t) * 64 + e] = XT[t * 65 + e];
    }
}

// ------- Kernel B: numpy f32 softmax + top-k, append into expert buckets -----
__global__ __launch_bounds__(THREADS)
void softmax_topk_kernel(const float* __restrict__ logits,
                         float* __restrict__ probs_out,
                         unsigned long long* __restrict__ bucket,
                         int* __restrict__ cnt,
                         const int* __restrict__ kptr, int T, int E)
{
    const int lane = threadIdx.x & 63;
    const int wid = threadIdx.x >> 6;
    int token = blockIdx.x * 4 + wid;
    if (token >= T) return;               // T % 4 == 0 here; guard for safety

    int k = *kptr;
    if (k > E) k = E;
    if (k > KMAX) k = KMAX;

    float z = logits[(size_t)token * 64 + lane];

    float m = z;
#pragma unroll
    for (int d = 1; d < 64; d <<= 1) m = fmaxf(m, __shfl_xor(m, d));

    float e32 = np_expf_avx512(z - m);

    __shared__ float sh[4][64];
    sh[wid][lane] = e32;
    __syncthreads();

    // numpy FLOAT_pairwise_sum, baseline npyv (SSE, 4 lanes), n=64:
    // R_j[l] = e[4j+l] + e[32+4j+l]; lanewise tree; SSE3 hadd horizontal.
    const float* row = sh[wid];
    float s[4];
#pragma unroll
    for (int l = 0; l < 4; ++l) {
        float R0 = row[ 0 + l] + row[32 + l];
        float R1 = row[ 4 + l] + row[36 + l];
        float R2 = row[ 8 + l] + row[40 + l];
        float R3 = row[12 + l] + row[44 + l];
        float R4 = row[16 + l] + row[48 + l];
        float R5 = row[20 + l] + row[52 + l];
        float R6 = row[24 + l] + row[56 + l];
        float R7 = row[28 + l] + row[60 + l];
        s[l] = ((R0 + R1) + (R2 + R3)) + ((R4 + R5) + (R6 + R7));
    }
    float S = (s[0] + s[1]) + (s[2] + s[3]);   // SSE3 hadd horizontal order

    float p = e32 / S;                    // CR f32 divide
    probs_out[(size_t)token * 64 + lane] = p;

    // per-token top-k on f32 p, tie -> lower expert id; append to buckets
    float pv = p;
    for (int j = 0; j < k; ++j) {
        float bp = pv;
        int be = lane;
#pragma unroll
        for (int d = 1; d < 64; d <<= 1) {
            float op = __shfl_xor(bp, d);
            int oe = __shfl_xor(be, d);
            if (op > bp || (op == bp && oe < be)) { bp = op; be = oe; }
        }
        if (lane == 0) {
            int slot = token * k + j;
            unsigned pbits = __float_as_uint(bp);
            unsigned long long key =
                ((unsigned long long)pbits << 32)
              | (unsigned long long)(0xFFFFFFFFu - (unsigned)slot);
            int pos = atomicAdd(&cnt[be], 1);
            if (pos < BUCKET) bucket[(size_t)be * BUCKET + pos] = key;
        }
        if (lane == be) pv = -1.0f;
    }
}

// ---------------- Kernel C: per-expert bitonic sort of its bucket ------------
// Key = (f32 prob bits << 32) | (0xFFFFFFFF - slot); descending u64 sort
// == prob desc, tie -> lower slot. Keys unique -> deterministic output.
#define MAXN 4096
__global__ __launch_bounds__(THREADS)
void expert_sort_kernel(const unsigned long long* __restrict__ bucket,
                        const int* __restrict__ cnt,
                        const int* __restrict__ kptr,
                        float* __restrict__ out_probs, float* __restrict__ out_idx,
                        int T, int E, int C)
{
    __shared__ unsigned long long keys[MAXN];
    const int e = blockIdx.x;
    const int tid = threadIdx.x;

    int k = *kptr;
    if (k > E) k = E;
    if (k > KMAX) k = KMAX;

    int n = cnt[e];
    if (n > BUCKET) n = BUCKET;

    for (int i = tid; i < n; i += THREADS)
        keys[i] = bucket[(size_t)e * BUCKET + i];

    int P = 1;
    while (P < n) P <<= 1;
    for (int i = n + tid; i < P; i += THREADS) keys[i] = 0ULL;
    __syncthreads();

    for (int size = 2; size <= P; size <<= 1) {
        for (int stride = size >> 1; stride > 0; stride >>= 1) {
            for (int i = tid; i < P; i += THREADS) {
                int j = i ^ stride;
                if (j > i) {
                    unsigned long long a = keys[i], bkey = keys[j];
                    bool up = ((i & size) == 0);
                    bool doswap = up ? (a < bkey) : (a > bkey);
                    if (doswap) { keys[i] = bkey; keys[j] = a; }
                }
            }
            __syncthreads();
        }
    }

    for (int c = tid; c < C; c += THREADS) {
        float prob, idxv;
        if (c < n) {
            unsigned long long kk = keys[c];
            prob = __uint_as_float((unsigned)(kk >> 32));
            unsigned slot = 0xFFFFFFFFu - (unsigned)(kk & 0xFFFFFFFFull);
            idxv = (float)(slot / (unsigned)k);
        } else {
            prob = 0.0f;
            idxv = -1.0f;
        }
        out_probs[(size_t)e * C + c] = prob;
        out_idx[(size_t)e * C + c] = idxv;
    }
}

extern "C" void kernel_launch(void* const* d_in, const int* in_sizes, int n_in,
                              void* d_out, int out_size, void* d_ws, size_t ws_size,
                              hipStream_t stream)
{
    const float* x   = (const float*)d_in[0];
    const float* W   = (const float*)d_in[1];
    const float* b   = (const float*)d_in[2];
    const int* kptr  = (const int*)d_in[3];

    const int E = in_sizes[2];            // 64
    const int D = in_sizes[1] / E;        // 1024
    const int T = in_sizes[0] / D;        // 32768
    const int C = (out_size - 2 * T * E) / (2 * E);   // 1280

    float* out_logits = (float*)d_out;
    float* out_probs  = out_logits + (size_t)T * E;
    float* out_eprobs = out_probs  + (size_t)T * E;
    float* out_eidx   = out_eprobs + (size_t)E * C;

    // workspace: WT (D*E f32) | cnt (E i32, padded to 256B) | bucket (E*BUCKET u64)
    float* WT  = (float*)d_ws;
    char*  ptr = (char*)d_ws + (size_t)D * E * sizeof(float);
    int*   cnt = (int*)ptr;
    ptr += 256;
    unsigned long long* bucket = (unsigned long long*)ptr;

    transpose_w_kernel<<<E, 256, 0, stream>>>(W, WT, D, E);
    zero_cnt_kernel<<<1, 64, 0, stream>>>(cnt, E);
    gemm_f32_kernel<<<T / 64, 512, 0, stream>>>(
        x, WT, b, out_logits, T, D, E);
    softmax_topk_kernel<<<(T + 3) / 4, THREADS, 0, stream>>>(
        out_logits, out_probs, bucket, cnt, kptr, T, E);
    expert_sort_kernel<<<E, THREADS, 0, stream>>>(
        bucket, cnt, kptr, out_eprobs, out_eidx, T, E, C);
}

// Round 22
// 289.733 us; speedup vs baseline: 1.7245x; 1.7245x over previous
//
#include <hip/hip_runtime.h>
#include <stdint.h>

// TopKRouter: T=32768, D=1024, E=64, k=2 (device scalar), C=1280 (from out_size).
//
// Correctness model (VERIFIED PASSING r19/r20/r21): np golden = numpy f32
// transliteration.
// logits = x @ W.T + b, K panels [0,512)[512,1024): single-accumulator
//   ascending-k f32 FMA chain per panel, panels summed left-to-right, + b.
// softmax f32: AVX512 FLOAT_exp (Cephes, FMA, rint, scalef); SSE npyv 4-lane
//   pairwise sum + SSE3 hadd horizontal; CR divide; exact max-subtract.
// top-k & capacity sort on f32 probs, ties -> lower index (stable).
// expert_indices stored as f32 values (-1.0f padding).
//
// r22: revert r21's bucket-append (65536 contended atomicAdds on 64 counters
// = 315us, Guideline-12 violation) back to r20's slot-indexed pf/eid writes +
// per-expert scan in kernel C. KEEP r21's LDS-staged W GEMM (verified win:
// gemm ~277 -> <150us).

#define THREADS 256
#define KMAX 16

// ---- numpy AVX512 FLOAT_exp replica: Cephes constants, FMA, rint quadrant ---
__device__ __forceinline__ float np_expf_avx512(float x)
{
    const float log2e = 1.442695040888963f;      // NPY_LOG2Ef
    float t = x * log2e;                          // separate mul (vmulps)
    float q = rintf(t);                           // roundscale nearest-even
    float r = fmaf(q, -0.693359375f, x);          // Cody-Waite hi (fma)
    r = fmaf(q, 2.12194440e-4f, r);               // Cody-Waite lo (fma)
    float y = 1.9875691500E-4f;                   // cephes_exp_p0..p5
    y = fmaf(y, r, 1.3981999507E-3f);
    y = fmaf(y, r, 8.3334519073E-3f);
    y = fmaf(y, r, 4.1665795894E-2f);
    y = fmaf(y, r, 1.6666665459E-1f);
    y = fmaf(y, r, 5.0000001201E-1f);
    float rr = r * r;                             // separate mul
    y = fmaf(y, rr, r);                           // poly*r^2 + r
    y = y + 1.0f;
    return ldexpf(y, (int)q);                     // vscalefps (q integral)
}

// ---------------- Kernel T: transpose W (E x D) -> WT (D x E, k-major) -------
__global__ __launch_bounds__(256)
void transpose_w_kernel(const float* __restrict__ W, float* __restrict__ WT,
                        int D, int E)
{
    const int e = blockIdx.x;
    for (int k = threadIdx.x; k < D; k += 256)
        WT[(size_t)k * E + e] = W[(size_t)e * D + k];
}

// ---------------- Kernel A: f32 logits, 512/512 K-panel FMA chains -----------
// Grid: T/64 blocks x 512 thr (8 waves). lane = token (64/block);
// wave w handles experts [8w, 8w+8). Per thread: acc[8] f32 chains.
// x staged transposed in LDS XT (stride 65); W-tile staged in LDS WS.
#define KC 64
__global__ __launch_bounds__(512, 4)
void gemm_f32_kernel(const float* __restrict__ x, const float* __restrict__ WT,
                     const float* __restrict__ bias,
                     float* __restrict__ logits_out, int T, int D, int E)
{
    const int tid  = threadIdx.x;
    const int lane = tid & 63;
    const int w    = tid >> 6;            // 0..7: expert octet
    const int tok0 = blockIdx.x * 64;

    __shared__ float XT[64 * 65];         // XT[k][t] stride 65; reused as LT
    __shared__ float WS[64 * 64];         // WS[k][e] contiguous

    float acc[8], ztot[8];
#pragma unroll
    for (int j = 0; j < 8; ++j) { acc[j] = 0.0f; ztot[j] = 0.0f; }

    const int cc = tid & 15;              // float4 index within a 64-float row
    const int r0 = tid >> 4;              // 0..31

    for (int kc = 0; kc < 1024; kc += KC) {
        __syncthreads();
        // stage XT[k][t] = x[tok0+t][kc+k]   (512 threads, 2 rows each)
        for (int r = r0; r < 64; r += 32) {
            float4 v = *reinterpret_cast<const float4*>(
                x + (size_t)(tok0 + r) * D + kc + 4 * cc);
            XT[(4 * cc + 0) * 65 + r] = v.x;
            XT[(4 * cc + 1) * 65 + r] = v.y;
            XT[(4 * cc + 2) * 65 + r] = v.z;
            XT[(4 * cc + 3) * 65 + r] = v.w;
        }
        // stage WS = WT[kc..kc+64)[0..64): 16KB contiguous, 2 float4/thread
        {
            const float4* src = reinterpret_cast<const float4*>(
                WT + (size_t)kc * 64);
            float4* dst = reinterpret_cast<float4*>(WS);
            dst[tid]       = src[tid];
            dst[tid + 512] = src[tid + 512];
        }
        __syncthreads();

#pragma unroll 8
        for (int k = 0; k < KC; ++k) {
            float xv = XT[k * 65 + lane];
            const float* wrow = WS + k * 64 + w * 8;   // wave-uniform
            float4 wv0 = *reinterpret_cast<const float4*>(wrow);
            float4 wv1 = *reinterpret_cast<const float4*>(wrow + 4);
            acc[0] = fmaf(xv, wv0.x, acc[0]);
            acc[1] = fmaf(xv, wv0.y, acc[1]);
            acc[2] = fmaf(xv, wv0.z, acc[2]);
            acc[3] = fmaf(xv, wv0.w, acc[3]);
            acc[4] = fmaf(xv, wv1.x, acc[4]);
            acc[5] = fmaf(xv, wv1.y, acc[5]);
            acc[6] = fmaf(xv, wv1.z, acc[6]);
            acc[7] = fmaf(xv, wv1.w, acc[7]);
        }
        // K panels 512/512: fold at tile boundaries only (bit-exact)
        int kend = kc + KC;
        if (kend == 512 || kend == 1024) {
#pragma unroll
            for (int j = 0; j < 8; ++j) { ztot[j] += acc[j]; acc[j] = 0.0f; }
        }
    }

#pragma unroll
    for (int j = 0; j < 8; ++j) ztot[j] += bias[w * 8 + j];

    // transpose via LDS (reuse XT as LT[t][e], stride 65), coalesced store
    __syncthreads();
#pragma unroll
    for (int j = 0; j < 8; ++j) XT[lane * 65 + w * 8 + j] = ztot[j];
    __syncthreads();
    for (int it = 0; it < 8; ++it) {
        int i = it * 512 + tid;           // 0..4095
        int t = i >> 6, e = i & 63;
        logits_out[(size_t)(tok0 + t) * 64 + e] = XT[t * 65 + e];
    }
}

// ------- Kernel B: numpy f32 softmax + per-token top-k (slot-indexed) --------
__global__ __launch_bounds__(THREADS)
void softmax_topk_kernel(const float* __restrict__ logits,
                         float* __restrict__ probs_out,
                         float* __restrict__ pf, int* __restrict__ eid,
                         const int* __restrict__ kptr, int T, int E)
{
    const int lane = threadIdx.x & 63;
    const int wid = threadIdx.x >> 6;
    int token = blockIdx.x * 4 + wid;
    if (token >= T) token = T - 1;

    int k = *kptr;
    if (k > E) k = E;
    if (k > KMAX) k = KMAX;

    float z = logits[(size_t)token * 64 + lane];

    float m = z;
#pragma unroll
    for (int d = 1; d < 64; d <<= 1) m = fmaxf(m, __shfl_xor(m, d));

    float e32 = np_expf_avx512(z - m);

    __shared__ float sh[4][64];
    sh[wid][lane] = e32;
    __syncthreads();

    // numpy FLOAT_pairwise_sum, baseline npyv (SSE, 4 lanes), n=64:
    // R_j[l] = e[4j+l] + e[32+4j+l]; lanewise tree; SSE3 hadd horizontal.
    const float* row = sh[wid];
    float s[4];
#pragma unroll
    for (int l = 0; l < 4; ++l) {
        float R0 = row[ 0 + l] + row[32 + l];
        float R1 = row[ 4 + l] + row[36 + l];
        float R2 = row[ 8 + l] + row[40 + l];
        float R3 = row[12 + l] + row[44 + l];
        float R4 = row[16 + l] + row[48 + l];
        float R5 = row[20 + l] + row[52 + l];
        float R6 = row[24 + l] + row[56 + l];
        float R7 = row[28 + l] + row[60 + l];
        s[l] = ((R0 + R1) + (R2 + R3)) + ((R4 + R5) + (R6 + R7));
    }
    float S = (s[0] + s[1]) + (s[2] + s[3]);   // SSE3 hadd horizontal order

    float p = e32 / S;                    // CR f32 divide
    probs_out[(size_t)token * 64 + lane] = p;

    // per-token top-k on f32 p, tie -> lower expert id
    float pv = p;
    for (int j = 0; j < k; ++j) {
        float bp = pv;
        int be = lane;
#pragma unroll
        for (int d = 1; d < 64; d <<= 1) {
            float op = __shfl_xor(bp, d);
            int oe = __shfl_xor(be, d);
            if (op > bp || (op == bp && oe < be)) { bp = op; be = oe; }
        }
        if (lane == 0) {
            int slot = token * k + j;
            pf[slot] = bp;
            eid[slot] = be;
        }
        if (lane == be) pv = -1.0f;
    }
}

// ---------------- Kernel C: per-expert gather + bitonic sort ----------------
// Key = (f32 prob bits << 32) | (0xFFFFFFFF - slot); descending u64 sort
// == prob desc, tie -> lower slot.
#define MAXN 4096
__global__ __launch_bounds__(THREADS)
void expert_sort_kernel(const float* __restrict__ pf, const int* __restrict__ eid,
                        const int* __restrict__ kptr,
                        float* __restrict__ out_probs, float* __restrict__ out_idx,
                        int T, int E, int C)
{
    __shared__ unsigned long long keys[MAXN];
    __shared__ int cnt;
    const int e = blockIdx.x;
    const int tid = threadIdx.x;
    if (tid == 0) cnt = 0;
    __syncthreads();

    int k = *kptr;
    if (k > E) k = E;
    if (k > KMAX) k = KMAX;
    const int nslots = T * k;

    for (int s = tid; s < nslots; s += THREADS) {
        if (eid[s] == e) {
            int pos = atomicAdd(&cnt, 1);
            if (pos < MAXN) {
                unsigned pbits = __float_as_uint(pf[s]);
                keys[pos] = ((unsigned long long)pbits << 32)
                          | (unsigned long long)(0xFFFFFFFFu - (unsigned)s);
            }
        }
    }
    __syncthreads();

    int n = cnt;
    if (n > MAXN) n = MAXN;

    int P = 1;
    while (P < n) P <<= 1;
    for (int i = n + tid; i < P; i += THREADS) keys[i] = 0ULL;
    __syncthreads();

    for (int size = 2; size <= P; size <<= 1) {
        for (int stride = size >> 1; stride > 0; stride >>= 1) {
            for (int i = tid; i < P; i += THREADS) {
                int j = i ^ stride;
                if (j > i) {
                    unsigned long long a = keys[i], bkey = keys[j];
                    bool up = ((i & size) == 0);
                    bool doswap = up ? (a < bkey) : (a > bkey);
                    if (doswap) { keys[i] = bkey; keys[j] = a; }
                }
            }
            __syncthreads();
        }
    }

    for (int c = tid; c < C; c += THREADS) {
        float prob, idxv;
        if (c < n) {
            unsigned long long kk = keys[c];
            prob = __uint_as_float((unsigned)(kk >> 32));
            unsigned slot = 0xFFFFFFFFu - (unsigned)(kk & 0xFFFFFFFFull);
            idxv = (float)(slot / (unsigned)k);
        } else {
            prob = 0.0f;
            idxv = -1.0f;
        }
        out_probs[(size_t)e * C + c] = prob;
        out_idx[(size_t)e * C + c] = idxv;
    }
}

extern "C" void kernel_launch(void* const* d_in, const int* in_sizes, int n_in,
                              void* d_out, int out_size, void* d_ws, size_t ws_size,
                              hipStream_t stream)
{
    const float* x   = (const float*)d_in[0];
    const float* W   = (const float*)d_in[1];
    const float* b   = (const float*)d_in[2];
    const int* kptr  = (const int*)d_in[3];

    const int E = in_sizes[2];            // 64
    const int D = in_sizes[1] / E;        // 1024
    const int T = in_sizes[0] / D;        // 32768
    const int C = (out_size - 2 * T * E) / (2 * E);   // 1280

    float* out_logits = (float*)d_out;
    float* out_probs  = out_logits + (size_t)T * E;
    float* out_eprobs = out_probs  + (size_t)T * E;
    float* out_eidx   = out_eprobs + (size_t)E * C;

    // workspace: WT (D*E f32) | pf (T*KMAX f32) | eid (T*KMAX i32)
    float* WT  = (float*)d_ws;
    float* pf  = (float*)((char*)d_ws + (size_t)D * E * sizeof(float));
    int*   eid = (int*)((char*)pf + (size_t)T * KMAX * sizeof(float));

    transpose_w_kernel<<<E, 256, 0, stream>>>(W, WT, D, E);
    gemm_f32_kernel<<<T / 64, 512, 0, stream>>>(
        x, WT, b, out_logits, T, D, E);
    softmax_topk_kernel<<<(T + 3) / 4, THREADS, 0, stream>>>(
        out_logits, out_probs, pf, eid, kptr, T, E);
    expert_sort_kernel<<<E, THREADS, 0, stream>>>(
        pf, eid, kptr, out_eprobs, out_eidx, T, E, C);
}

// Round 23
// 173.706 us; speedup vs baseline: 2.8764x; 1.6680x over previous
//
#include <hip/hip_runtime.h>
#include <stdint.h>

// TopKRouter: T=32768, D=1024, E=64, k=2 (device scalar), C=1280 (from out_size).
//
// Correctness model (VERIFIED PASSING r19-r22): np golden = numpy f32
// transliteration.
// logits = x @ W.T + b, K panels [0,512)[512,1024): single-accumulator
//   ascending-k f32 FMA chain per panel, panels summed left-to-right, + b.
// softmax f32: AVX512 FLOAT_exp (Cephes, FMA, rint, scalef); SSE npyv 4-lane
//   pairwise sum + SSE3 hadd horizontal; CR divide; exact max-subtract.
// top-k & capacity sort on f32 probs, ties -> lower index (stable).
// expert_indices stored as f32 values (-1.0f padding).
//
// r23: expert_sort gather scan was the bottleneck (166us, Occ 2.5%, VALU 2%:
// 64 blocks x 4 waves scalar-scanning 65536 eids = latency-bound). Widen to
// 1024 thr/block (16 waves) + int4-vectorized eid scan (16 independent 16B
// loads/thread). GEMM + softmax frozen (verified).

#define THREADS 256
#define TSORT 1024
#define KMAX 16

// ---- numpy AVX512 FLOAT_exp replica: Cephes constants, FMA, rint quadrant ---
__device__ __forceinline__ float np_expf_avx512(float x)
{
    const float log2e = 1.442695040888963f;      // NPY_LOG2Ef
    float t = x * log2e;                          // separate mul (vmulps)
    float q = rintf(t);                           // roundscale nearest-even
    float r = fmaf(q, -0.693359375f, x);          // Cody-Waite hi (fma)
    r = fmaf(q, 2.12194440e-4f, r);               // Cody-Waite lo (fma)
    float y = 1.9875691500E-4f;                   // cephes_exp_p0..p5
    y = fmaf(y, r, 1.3981999507E-3f);
    y = fmaf(y, r, 8.3334519073E-3f);
    y = fmaf(y, r, 4.1665795894E-2f);
    y = fmaf(y, r, 1.6666665459E-1f);
    y = fmaf(y, r, 5.0000001201E-1f);
    float rr = r * r;                             // separate mul
    y = fmaf(y, rr, r);                           // poly*r^2 + r
    y = y + 1.0f;
    return ldexpf(y, (int)q);                     // vscalefps (q integral)
}

// ---------------- Kernel T: transpose W (E x D) -> WT (D x E, k-major) -------
__global__ __launch_bounds__(256)
void transpose_w_kernel(const float* __restrict__ W, float* __restrict__ WT,
                        int D, int E)
{
    const int e = blockIdx.x;
    for (int k = threadIdx.x; k < D; k += 256)
        WT[(size_t)k * E + e] = W[(size_t)e * D + k];
}

// ---------------- Kernel A: f32 logits, 512/512 K-panel FMA chains -----------
// Grid: T/64 blocks x 512 thr (8 waves). lane = token (64/block);
// wave w handles experts [8w, 8w+8). Per thread: acc[8] f32 chains.
// x staged transposed in LDS XT (stride 65); W-tile staged in LDS WS.
#define KC 64
__global__ __launch_bounds__(512, 4)
void gemm_f32_kernel(const float* __restrict__ x, const float* __restrict__ WT,
                     const float* __restrict__ bias,
                     float* __restrict__ logits_out, int T, int D, int E)
{
    const int tid  = threadIdx.x;
    const int lane = tid & 63;
    const int w    = tid >> 6;            // 0..7: expert octet
    const int tok0 = blockIdx.x * 64;

    __shared__ float XT[64 * 65];         // XT[k][t] stride 65; reused as LT
    __shared__ float WS[64 * 64];         // WS[k][e] contiguous

    float acc[8], ztot[8];
#pragma unroll
    for (int j = 0; j < 8; ++j) { acc[j] = 0.0f; ztot[j] = 0.0f; }

    const int cc = tid & 15;              // float4 index within a 64-float row
    const int r0 = tid >> 4;              // 0..31

    for (int kc = 0; kc < 1024; kc += KC) {
        __syncthreads();
        // stage XT[k][t] = x[tok0+t][kc+k]   (512 threads, 2 rows each)
        for (int r = r0; r < 64; r += 32) {
            float4 v = *reinterpret_cast<const float4*>(
                x + (size_t)(tok0 + r) * D + kc + 4 * cc);
            XT[(4 * cc + 0) * 65 + r] = v.x;
            XT[(4 * cc + 1) * 65 + r] = v.y;
            XT[(4 * cc + 2) * 65 + r] = v.z;
            XT[(4 * cc + 3) * 65 + r] = v.w;
        }
        // stage WS = WT[kc..kc+64)[0..64): 16KB contiguous, 2 float4/thread
        {
            const float4* src = reinterpret_cast<const float4*>(
                WT + (size_t)kc * 64);
            float4* dst = reinterpret_cast<float4*>(WS);
            dst[tid]       = src[tid];
            dst[tid + 512] = src[tid + 512];
        }
        __syncthreads();

#pragma unroll 8
        for (int k = 0; k < KC; ++k) {
            float xv = XT[k * 65 + lane];
            const float* wrow = WS + k * 64 + w * 8;   // wave-uniform
            float4 wv0 = *reinterpret_cast<const float4*>(wrow);
            float4 wv1 = *reinterpret_cast<const float4*>(wrow + 4);
            acc[0] = fmaf(xv, wv0.x, acc[0]);
            acc[1] = fmaf(xv, wv0.y, acc[1]);
            acc[2] = fmaf(xv, wv0.z, acc[2]);
            acc[3] = fmaf(xv, wv0.w, acc[3]);
            acc[4] = fmaf(xv, wv1.x, acc[4]);
            acc[5] = fmaf(xv, wv1.y, acc[5]);
            acc[6] = fmaf(xv, wv1.z, acc[6]);
            acc[7] = fmaf(xv, wv1.w, acc[7]);
        }
        // K panels 512/512: fold at tile boundaries only (bit-exact)
        int kend = kc + KC;
        if (kend == 512 || kend == 1024) {
#pragma unroll
            for (int j = 0; j < 8; ++j) { ztot[j] += acc[j]; acc[j] = 0.0f; }
        }
    }

#pragma unroll
    for (int j = 0; j < 8; ++j) ztot[j] += bias[w * 8 + j];

    // transpose via LDS (reuse XT as LT[t][e], stride 65), coalesced store
    __syncthreads();
#pragma unroll
    for (int j = 0; j < 8; ++j) XT[lane * 65 + w * 8 + j] = ztot[j];
    __syncthreads();
    for (int it = 0; it < 8; ++it) {
        int i = it * 512 + tid;           // 0..4095
        int t = i >> 6, e = i & 63;
        logits_out[(size_t)(tok0 + t) * 64 + e] = XT[t * 65 + e];
    }
}

// ------- Kernel B: numpy f32 softmax + per-token top-k (slot-indexed) --------
__global__ __launch_bounds__(THREADS)
void softmax_topk_kernel(const float* __restrict__ logits,
                         float* __restrict__ probs_out,
                         float* __restrict__ pf, int* __restrict__ eid,
                         const int* __restrict__ kptr, int T, int E)
{
    const int lane = threadIdx.x & 63;
    const int wid = threadIdx.x >> 6;
    int token = blockIdx.x * 4 + wid;
    if (token >= T) token = T - 1;

    int k = *kptr;
    if (k > E) k = E;
    if (k > KMAX) k = KMAX;

    float z = logits[(size_t)token * 64 + lane];

    float m = z;
#pragma unroll
    for (int d = 1; d < 64; d <<= 1) m = fmaxf(m, __shfl_xor(m, d));

    float e32 = np_expf_avx512(z - m);

    __shared__ float sh[4][64];
    sh[wid][lane] = e32;
    __syncthreads();

    // numpy FLOAT_pairwise_sum, baseline npyv (SSE, 4 lanes), n=64:
    // R_j[l] = e[4j+l] + e[32+4j+l]; lanewise tree; SSE3 hadd horizontal.
    const float* row = sh[wid];
    float s[4];
#pragma unroll
    for (int l = 0; l < 4; ++l) {
        float R0 = row[ 0 + l] + row[32 + l];
        float R1 = row[ 4 + l] + row[36 + l];
        float R2 = row[ 8 + l] + row[40 + l];
        float R3 = row[12 + l] + row[44 + l];
        float R4 = row[16 + l] + row[48 + l];
        float R5 = row[20 + l] + row[52 + l];
        float R6 = row[24 + l] + row[56 + l];
        float R7 = row[28 + l] + row[60 + l];
        s[l] = ((R0 + R1) + (R2 + R3)) + ((R4 + R5) + (R6 + R7));
    }
    float S = (s[0] + s[1]) + (s[2] + s[3]);   // SSE3 hadd horizontal order

    float p = e32 / S;                    // CR f32 divide
    probs_out[(size_t)token * 64 + lane] = p;

    // per-token top-k on f32 p, tie -> lower expert id
    float pv = p;
    for (int j = 0; j < k; ++j) {
        float bp = pv;
        int be = lane;
#pragma unroll
        for (int d = 1; d < 64; d <<= 1) {
            float op = __shfl_xor(bp, d);
            int oe = __shfl_xor(be, d);
            if (op > bp || (op == bp && oe < be)) { bp = op; be = oe; }
        }
        if (lane == 0) {
            int slot = token * k + j;
            pf[slot] = bp;
            eid[slot] = be;
        }
        if (lane == be) pv = -1.0f;
    }
}

// ---------------- Kernel C: per-expert gather + bitonic sort ----------------
// Key = (f32 prob bits << 32) | (0xFFFFFFFF - slot); descending u64 sort
// == prob desc, tie -> lower slot. 1024 thr, int4 eid scan (r23).
#define MAXN 4096
__global__ __launch_bounds__(TSORT)
void expert_sort_kernel(const float* __restrict__ pf, const int* __restrict__ eid,
                        const int* __restrict__ kptr,
                        float* __restrict__ out_probs, float* __restrict__ out_idx,
                        int T, int E, int C)
{
    __shared__ unsigned long long keys[MAXN];
    __shared__ int cnt;
    const int e = blockIdx.x;
    const int tid = threadIdx.x;
    if (tid == 0) cnt = 0;
    __syncthreads();

    int k = *kptr;
    if (k > E) k = E;
    if (k > KMAX) k = KMAX;
    const int nslots = T * k;

    // vectorized scan: int4 loads (nslots % 4 == 0 for T mult of 64)
    const int4* eid4 = reinterpret_cast<const int4*>(eid);
    const int nvec = nslots >> 2;
    for (int v = tid; v < nvec; v += TSORT) {
        int4 e4 = eid4[v];
        int sbase = v << 2;
        if (e4.x == e) {
            int pos = atomicAdd(&cnt, 1);
            if (pos < MAXN) keys[pos] =
                ((unsigned long long)__float_as_uint(pf[sbase + 0]) << 32)
              | (unsigned long long)(0xFFFFFFFFu - (unsigned)(sbase + 0));
        }
        if (e4.y == e) {
            int pos = atomicAdd(&cnt, 1);
            if (pos < MAXN) keys[pos] =
                ((unsigned long long)__float_as_uint(pf[sbase + 1]) << 32)
              | (unsigned long long)(0xFFFFFFFFu - (unsigned)(sbase + 1));
        }
        if (e4.z == e) {
            int pos = atomicAdd(&cnt, 1);
            if (pos < MAXN) keys[pos] =
                ((unsigned long long)__float_as_uint(pf[sbase + 2]) << 32)
              | (unsigned long long)(0xFFFFFFFFu - (unsigned)(sbase + 2));
        }
        if (e4.w == e) {
            int pos = atomicAdd(&cnt, 1);
            if (pos < MAXN) keys[pos] =
                ((unsigned long long)__float_as_uint(pf[sbase + 3]) << 32)
              | (unsigned long long)(0xFFFFFFFFu - (unsigned)(sbase + 3));
        }
    }
    __syncthreads();

    int n = cnt;
    if (n > MAXN) n = MAXN;

    int P = 1;
    while (P < n) P <<= 1;
    for (int i = n + tid; i < P; i += TSORT) keys[i] = 0ULL;
    __syncthreads();

    for (int size = 2; size <= P; size <<= 1) {
        for (int stride = size >> 1; stride > 0; stride >>= 1) {
            for (int i = tid; i < P; i += TSORT) {
                int j = i ^ stride;
                if (j > i) {
                    unsigned long long a = keys[i], bkey = keys[j];
                    bool up = ((i & size) == 0);
                    bool doswap = up ? (a < bkey) : (a > bkey);
                    if (doswap) { keys[i] = bkey; keys[j] = a; }
                }
            }
            __syncthreads();
        }
    }

    for (int c = tid; c < C; c += TSORT) {
        float prob, idxv;
        if (c < n) {
            unsigned long long kk = keys[c];
            prob = __uint_as_float((unsigned)(kk >> 32));
            unsigned slot = 0xFFFFFFFFu - (unsigned)(kk & 0xFFFFFFFFull);
            idxv = (float)(slot / (unsigned)k);
        } else {
            prob = 0.0f;
            idxv = -1.0f;
        }
        out_probs[(size_t)e * C + c] = prob;
        out_idx[(size_t)e * C + c] = idxv;
    }
}

extern "C" void kernel_launch(void* const* d_in, const int* in_sizes, int n_in,
                              void* d_out, int out_size, void* d_ws, size_t ws_size,
                              hipStream_t stream)
{
    const float* x   = (const float*)d_in[0];
    const float* W   = (const float*)d_in[1];
    const float* b   = (const float*)d_in[2];
    const int* kptr  = (const int*)d_in[3];

    const int E = in_sizes[2];            // 64
    const int D = in_sizes[1] / E;        // 1024
    const int T = in_sizes[0] / D;        // 32768
    const int C = (out_size - 2 * T * E) / (2 * E);   // 1280

    float* out_logits = (float*)d_out;
    float* out_probs  = out_logits + (size_t)T * E;
    float* out_eprobs = out_probs  + (size_t)T * E;
    float* out_eidx   = out_eprobs + (size_t)E * C;

    // workspace: WT (D*E f32) | pf (T*KMAX f32) | eid (T*KMAX i32)
    float* WT  = (float*)d_ws;
    float* pf  = (float*)((char*)d_ws + (size_t)D * E * sizeof(float));
    int*   eid = (int*)((char*)pf + (size_t)T * KMAX * sizeof(float));

    transpose_w_kernel<<<E, 256, 0, stream>>>(W, WT, D, E);
    gemm_f32_kernel<<<T / 64, 512, 0, stream>>>(
        x, WT, b, out_logits, T, D, E);
    softmax_topk_kernel<<<(T + 3) / 4, THREADS, 0, stream>>>(
        out_logits, out_probs, pf, eid, kptr, T, E);
    expert_sort_kernel<<<E, TSORT, 0, stream>>>(
        pf, eid, kptr, out_eprobs, out_eidx, T, E, C);
}

// Round 24
// 168.258 us; speedup vs baseline: 2.9696x; 1.0324x over previous
//
#include <hip/hip_runtime.h>
#include <stdint.h>

// TopKRouter: T=32768, D=1024, E=64, k=2 (device scalar), C=1280 (from out_size).
//
// Correctness model (VERIFIED PASSING r19-r23): np golden = numpy f32
// transliteration.
// logits = x @ W.T + b, K panels [0,512)[512,1024): single-accumulator
//   ascending-k f32 FMA chain per panel, panels summed left-to-right, + b:
//   z = (c1 + c2) + b. softmax f32: AVX512 FLOAT_exp (Cephes, FMA, rint,
//   scalef); SSE npyv 4-lane pairwise sum + SSE3 hadd horizontal; CR divide;
//   exact max-subtract. top-k & capacity sort: ties -> lower index (stable).
// expert_indices stored as f32 values (-1.0f padding).
//
// r24: K-split x2 along the reference's own panel seam. Two blocks per token
// tile compute c1=chain(0:512), c2=chain(512:1024) independently (serial
// chains untouched); kernel B computes z=(p0+p1)+bias — the exact r23 fold
// order. Grid 512->1024 blocks = 4 blocks/CU = 100% occupancy (r23 was
// grid-limited: 43% occ, VALUBusy 29%, gemm 136us vs 27us VALU floor).

#define THREADS 256
#define TSORT 1024
#define KMAX 16

// ---- numpy AVX512 FLOAT_exp replica: Cephes constants, FMA, rint quadrant ---
__device__ __forceinline__ float np_expf_avx512(float x)
{
    const float log2e = 1.442695040888963f;      // NPY_LOG2Ef
    float t = x * log2e;                          // separate mul (vmulps)
    float q = rintf(t);                           // roundscale nearest-even
    float r = fmaf(q, -0.693359375f, x);          // Cody-Waite hi (fma)
    r = fmaf(q, 2.12194440e-4f, r);               // Cody-Waite lo (fma)
    float y = 1.9875691500E-4f;                   // cephes_exp_p0..p5
    y = fmaf(y, r, 1.3981999507E-3f);
    y = fmaf(y, r, 8.3334519073E-3f);
    y = fmaf(y, r, 4.1665795894E-2f);
    y = fmaf(y, r, 1.6666665459E-1f);
    y = fmaf(y, r, 5.0000001201E-1f);
    float rr = r * r;                             // separate mul
    y = fmaf(y, rr, r);                           // poly*r^2 + r
    y = y + 1.0f;
    return ldexpf(y, (int)q);                     // vscalefps (q integral)
}

// ---------------- Kernel T: transpose W (E x D) -> WT (D x E, k-major) -------
__global__ __launch_bounds__(256)
void transpose_w_kernel(const float* __restrict__ W, float* __restrict__ WT,
                        int D, int E)
{
    const int e = blockIdx.x;
    for (int k = threadIdx.x; k < D; k += 256)
        WT[(size_t)k * E + e] = W[(size_t)e * D + k];
}

// ------- Kernel A: f32 partial logits, one 512-wide K-panel chain per block --
// Grid: (T/64)*2 blocks x 512 thr (8 waves). kh = blockIdx.x & 1 selects the
// K panel; tile = blockIdx.x >> 1 selects 64 tokens. lane = token; wave w =
// experts [8w, 8w+8). Per thread: acc[8] f32 chains (ascending k, serial).
#define KC 64
__global__ __launch_bounds__(512, 8)
void gemm_partial_kernel(const float* __restrict__ x, const float* __restrict__ WT,
                         float* __restrict__ partial, int T, int D, int E)
{
    const int tid  = threadIdx.x;
    const int lane = tid & 63;
    const int w    = tid >> 6;            // 0..7: expert octet
    const int kh   = blockIdx.x & 1;      // K panel
    const int tok0 = (blockIdx.x >> 1) * 64;
    const int kbeg = kh * 512;

    __shared__ float XT[64 * 65];         // XT[k][t] stride 65; reused as LT
    __shared__ float WS[64 * 64];         // WS[k][e] contiguous

    float acc[8];
#pragma unroll
    for (int j = 0; j < 8; ++j) acc[j] = 0.0f;

    const int cc = tid & 15;              // float4 index within a 64-float row
    const int r0 = tid >> 4;              // 0..31

    for (int kc = kbeg; kc < kbeg + 512; kc += KC) {
        __syncthreads();
        // stage XT[k][t] = x[tok0+t][kc+k]   (512 threads, 2 rows each)
        for (int r = r0; r < 64; r += 32) {
            float4 v = *reinterpret_cast<const float4*>(
                x + (size_t)(tok0 + r) * D + kc + 4 * cc);
            XT[(4 * cc + 0) * 65 + r] = v.x;
            XT[(4 * cc + 1) * 65 + r] = v.y;
            XT[(4 * cc + 2) * 65 + r] = v.z;
            XT[(4 * cc + 3) * 65 + r] = v.w;
        }
        // stage WS = WT[kc..kc+64)[0..64): 16KB contiguous, 2 float4/thread
        {
            const float4* src = reinterpret_cast<const float4*>(
                WT + (size_t)kc * 64);
            float4* dst = reinterpret_cast<float4*>(WS);
            dst[tid]       = src[tid];
            dst[tid + 512] = src[tid + 512];
        }
        __syncthreads();

#pragma unroll 8
        for (int k = 0; k < KC; ++k) {
            float xv = XT[k * 65 + lane];
            const float* wrow = WS + k * 64 + w * 8;   // wave-uniform
            float4 wv0 = *reinterpret_cast<const float4*>(wrow);
            float4 wv1 = *reinterpret_cast<const float4*>(wrow + 4);
            acc[0] = fmaf(xv, wv0.x, acc[0]);
            acc[1] = fmaf(xv, wv0.y, acc[1]);
            acc[2] = fmaf(xv, wv0.z, acc[2]);
            acc[3] = fmaf(xv, wv0.w, acc[3]);
            acc[4] = fmaf(xv, wv1.x, acc[4]);
            acc[5] = fmaf(xv, wv1.y, acc[5]);
            acc[6] = fmaf(xv, wv1.z, acc[6]);
            acc[7] = fmaf(xv, wv1.w, acc[7]);
        }
    }

    // transpose via LDS (reuse XT as LT[t][e], stride 65), coalesced store
    __syncthreads();
#pragma unroll
    for (int j = 0; j < 8; ++j) XT[lane * 65 + w * 8 + j] = acc[j];
    __syncthreads();
    float* out = partial + (size_t)kh * T * 64;
    for (int it = 0; it < 8; ++it) {
        int i = it * 512 + tid;           // 0..4095
        int t = i >> 6, e = i & 63;
        out[(size_t)(tok0 + t) * 64 + e] = XT[t * 65 + e];
    }
}

// --- Kernel B: combine (p0+p1)+bias, numpy f32 softmax, per-token top-k -----
__global__ __launch_bounds__(THREADS)
void softmax_topk_kernel(const float* __restrict__ part0,
                         const float* __restrict__ part1,
                         const float* __restrict__ bias,
                         float* __restrict__ logits_out,
                         float* __restrict__ probs_out,
                         float* __restrict__ pf, int* __restrict__ eid,
                         const int* __restrict__ kptr, int T, int E)
{
    const int lane = threadIdx.x & 63;
    const int wid = threadIdx.x >> 6;
    int token = blockIdx.x * 4 + wid;
    if (token >= T) token = T - 1;

    int k = *kptr;
    if (k > E) k = E;
    if (k > KMAX) k = KMAX;

    size_t idx = (size_t)token * 64 + lane;
    // z = (c1 + c2) + b  -- exact reference panel-fold order
    float z = (part0[idx] + part1[idx]) + bias[lane];
    logits_out[idx] = z;

    float m = z;
#pragma unroll
    for (int d = 1; d < 64; d <<= 1) m = fmaxf(m, __shfl_xor(m, d));

    float e32 = np_expf_avx512(z - m);

    __shared__ float sh[4][64];
    sh[wid][lane] = e32;
    __syncthreads();

    // numpy FLOAT_pairwise_sum, baseline npyv (SSE, 4 lanes), n=64:
    // R_j[l] = e[4j+l] + e[32+4j+l]; lanewise tree; SSE3 hadd horizontal.
    const float* row = sh[wid];
    float s[4];
#pragma unroll
    for (int l = 0; l < 4; ++l) {
        float R0 = row[ 0 + l] + row[32 + l];
        float R1 = row[ 4 + l] + row[36 + l];
        float R2 = row[ 8 + l] + row[40 + l];
        float R3 = row[12 + l] + row[44 + l];
        float R4 = row[16 + l] + row[48 + l];
        float R5 = row[20 + l] + row[52 + l];
        float R6 = row[24 + l] + row[56 + l];
        float R7 = row[28 + l] + row[60 + l];
        s[l] = ((R0 + R1) + (R2 + R3)) + ((R4 + R5) + (R6 + R7));
    }
    float S = (s[0] + s[1]) + (s[2] + s[3]);   // SSE3 hadd horizontal order

    float p = e32 / S;                    // CR f32 divide
    probs_out[idx] = p;

    // per-token top-k on f32 p, tie -> lower expert id
    float pv = p;
    for (int j = 0; j < k; ++j) {
        float bp = pv;
        int be = lane;
#pragma unroll
        for (int d = 1; d < 64; d <<= 1) {
            float op = __shfl_xor(bp, d);
            int oe = __shfl_xor(be, d);
            if (op > bp || (op == bp && oe < be)) { bp = op; be = oe; }
        }
        if (lane == 0) {
            int slot = token * k + j;
            pf[slot] = bp;
            eid[slot] = be;
        }
        if (lane == be) pv = -1.0f;
    }
}

// ---------------- Kernel C: per-expert gather + bitonic sort ----------------
// Key = (f32 prob bits << 32) | (0xFFFFFFFF - slot); descending u64 sort
// == prob desc, tie -> lower slot. 1024 thr, int4 eid scan.
#define MAXN 4096
__global__ __launch_bounds__(TSORT)
void expert_sort_kernel(const float* __restrict__ pf, const int* __restrict__ eid,
                        const int* __restrict__ kptr,
                        float* __restrict__ out_probs, float* __restrict__ out_idx,
                        int T, int E, int C)
{
    __shared__ unsigned long long keys[MAXN];
    __shared__ int cnt;
    const int e = blockIdx.x;
    const int tid = threadIdx.x;
    if (tid == 0) cnt = 0;
    __syncthreads();

    int k = *kptr;
    if (k > E) k = E;
    if (k > KMAX) k = KMAX;
    const int nslots = T * k;

    // vectorized scan: int4 loads (nslots % 4 == 0 for T mult of 64)
    const int4* eid4 = reinterpret_cast<const int4*>(eid);
    const int nvec = nslots >> 2;
    for (int v = tid; v < nvec; v += TSORT) {
        int4 e4 = eid4[v];
        int sbase = v << 2;
        if (e4.x == e) {
            int pos = atomicAdd(&cnt, 1);
            if (pos < MAXN) keys[pos] =
                ((unsigned long long)__float_as_uint(pf[sbase + 0]) << 32)
              | (unsigned long long)(0xFFFFFFFFu - (unsigned)(sbase + 0));
        }
        if (e4.y == e) {
            int pos = atomicAdd(&cnt, 1);
            if (pos < MAXN) keys[pos] =
                ((unsigned long long)__float_as_uint(pf[sbase + 1]) << 32)
              | (unsigned long long)(0xFFFFFFFFu - (unsigned)(sbase + 1));
        }
        if (e4.z == e) {
            int pos = atomicAdd(&cnt, 1);
            if (pos < MAXN) keys[pos] =
                ((unsigned long long)__float_as_uint(pf[sbase + 2]) << 32)
              | (unsigned long long)(0xFFFFFFFFu - (unsigned)(sbase + 2));
        }
        if (e4.w == e) {
            int pos = atomicAdd(&cnt, 1);
            if (pos < MAXN) keys[pos] =
                ((unsigned long long)__float_as_uint(pf[sbase + 3]) << 32)
              | (unsigned long long)(0xFFFFFFFFu - (unsigned)(sbase + 3));
        }
    }
    __syncthreads();

    int n = cnt;
    if (n > MAXN) n = MAXN;

    int P = 1;
    while (P < n) P <<= 1;
    for (int i = n + tid; i < P; i += TSORT) keys[i] = 0ULL;
    __syncthreads();

    for (int size = 2; size <= P; size <<= 1) {
        for (int stride = size >> 1; stride > 0; stride >>= 1) {
            for (int i = tid; i < P; i += TSORT) {
                int j = i ^ stride;
                if (j > i) {
                    unsigned long long a = keys[i], bkey = keys[j];
                    bool up = ((i & size) == 0);
                    bool doswap = up ? (a < bkey) : (a > bkey);
                    if (doswap) { keys[i] = bkey; keys[j] = a; }
                }
            }
            __syncthreads();
        }
    }

    for (int c = tid; c < C; c += TSORT) {
        float prob, idxv;
        if (c < n) {
            unsigned long long kk = keys[c];
            prob = __uint_as_float((unsigned)(kk >> 32));
            unsigned slot = 0xFFFFFFFFu - (unsigned)(kk & 0xFFFFFFFFull);
            idxv = (float)(slot / (unsigned)k);
        } else {
            prob = 0.0f;
            idxv = -1.0f;
        }
        out_probs[(size_t)e * C + c] = prob;
        out_idx[(size_t)e * C + c] = idxv;
    }
}

extern "C" void kernel_launch(void* const* d_in, const int* in_sizes, int n_in,
                              void* d_out, int out_size, void* d_ws, size_t ws_size,
                              hipStream_t stream)
{
    const float* x   = (const float*)d_in[0];
    const float* W   = (const float*)d_in[1];
    const float* b   = (const float*)d_in[2];
    const int* kptr  = (const int*)d_in[3];

    const int E = in_sizes[2];            // 64
    const int D = in_sizes[1] / E;        // 1024
    const int T = in_sizes[0] / D;        // 32768
    const int C = (out_size - 2 * T * E) / (2 * E);   // 1280

    float* out_logits = (float*)d_out;
    float* out_probs  = out_logits + (size_t)T * E;
    float* out_eprobs = out_probs  + (size_t)T * E;
    float* out_eidx   = out_eprobs + (size_t)E * C;

    // workspace: WT (D*E f32) | pf (T*KMAX f32) | eid (T*KMAX i32) | partial
    float* WT  = (float*)d_ws;
    float* pf  = (float*)((char*)d_ws + (size_t)D * E * sizeof(float));
    int*   eid = (int*)((char*)pf + (size_t)T * KMAX * sizeof(float));
    float* partial = (float*)((char*)eid + (size_t)T * KMAX * sizeof(int));

    transpose_w_kernel<<<E, 256, 0, stream>>>(W, WT, D, E);
    gemm_partial_kernel<<<(T / 64) * 2, 512, 0, stream>>>(
        x, WT, partial, T, D, E);
    softmax_topk_kernel<<<(T + 3) / 4, THREADS, 0, stream>>>(
        partial, partial + (size_t)T * 64, b, out_logits, out_probs,
        pf, eid, kptr, T, E);
    expert_sort_kernel<<<E, TSORT, 0, stream>>>(
        pf, eid, kptr, out_eprobs, out_eidx, T, E, C);
}

// Round 25
// 161.819 us; speedup vs baseline: 3.0878x; 1.0398x over previous
//
#include <hip/hip_runtime.h>
#include <stdint.h>

// TopKRouter: T=32768, D=1024, E=64, k=2 (device scalar), C=1280 (from out_size).
//
// Correctness model (VERIFIED PASSING r19-r24): np golden = numpy f32
// transliteration.
// logits = x @ W.T + b, K panels [0,512)[512,1024): single-accumulator
//   ascending-k f32 FMA chain per panel, panels summed left-to-right, + b:
//   z = (c1 + c2) + b. softmax f32: AVX512 FLOAT_exp (Cephes, FMA, rint,
//   scalef); SSE npyv 4-lane pairwise sum + SSE3 hadd horizontal; CR divide;
//   exact max-subtract. top-k & capacity sort: ties -> lower index (stable).
// expert_indices stored as f32 values (-1.0f padding).
//
// r25: T14 async-STAGE split in the GEMM. r24: staging globals sat between
// barriers (exposed ~500cyc/tile) and launch_bounds(512,8) left VGPR=20 (no
// pipelining headroom). Now: issue next-tile global loads into regs BEFORE
// the inner loop (latency hides under 64 k-steps of FMA), write LDS after
// the barrier. Chain order/order-of-adds untouched (bit-exact).

#define THREADS 256
#define TSORT 1024
#define KMAX 16

// ---- numpy AVX512 FLOAT_exp replica: Cephes constants, FMA, rint quadrant ---
__device__ __forceinline__ float np_expf_avx512(float x)
{
    const float log2e = 1.442695040888963f;      // NPY_LOG2Ef
    float t = x * log2e;                          // separate mul (vmulps)
    float q = rintf(t);                           // roundscale nearest-even
    float r = fmaf(q, -0.693359375f, x);          // Cody-Waite hi (fma)
    r = fmaf(q, 2.12194440e-4f, r);               // Cody-Waite lo (fma)
    float y = 1.9875691500E-4f;                   // cephes_exp_p0..p5
    y = fmaf(y, r, 1.3981999507E-3f);
    y = fmaf(y, r, 8.3334519073E-3f);
    y = fmaf(y, r, 4.1665795894E-2f);
    y = fmaf(y, r, 1.6666665459E-1f);
    y = fmaf(y, r, 5.0000001201E-1f);
    float rr = r * r;                             // separate mul
    y = fmaf(y, rr, r);                           // poly*r^2 + r
    y = y + 1.0f;
    return ldexpf(y, (int)q);                     // vscalefps (q integral)
}

// ---------------- Kernel T: transpose W (E x D) -> WT (D x E, k-major) -------
__global__ __launch_bounds__(256)
void transpose_w_kernel(const float* __restrict__ W, float* __restrict__ WT,
                        int D, int E)
{
    const int e = blockIdx.x;
    for (int k = threadIdx.x; k < D; k += 256)
        WT[(size_t)k * E + e] = W[(size_t)e * D + k];
}

// ------- Kernel A: f32 partial logits, one 512-wide K-panel chain per block --
// Grid: (T/64)*2 blocks x 512 thr (8 waves). kh = blockIdx.x & 1 selects the
// K panel; tile = blockIdx.x >> 1 selects 64 tokens. lane = token; wave w =
// experts [8w, 8w+8). Per thread: acc[8] f32 chains (ascending k, serial).
// T14: next-tile global loads issued before the inner loop (regs), LDS
// writes after the barrier.
#define KC 64
#define NTILE 8                       // 512 / KC
__global__ __launch_bounds__(512, 8)
void gemm_partial_kernel(const float* __restrict__ x, const float* __restrict__ WT,
                         float* __restrict__ partial, int T, int D, int E)
{
    const int tid  = threadIdx.x;
    const int lane = tid & 63;
    const int w    = tid >> 6;            // 0..7: expert octet
    const int kh   = blockIdx.x & 1;      // K panel
    const int tok0 = (blockIdx.x >> 1) * 64;
    const int kbeg = kh * 512;

    __shared__ float XT[64 * 65];         // XT[k][t] stride 65; reused as LT
    __shared__ float WS[64 * 64];         // WS[k][e] contiguous

    float acc[8];
#pragma unroll
    for (int j = 0; j < 8; ++j) acc[j] = 0.0f;

    const int cc = tid & 15;              // float4 index within a 64-float row
    const int r0 = tid >> 4;              // 0..31 (two x rows: r0, r0+32)

    // ---- stage registers ----
    float4 xr0, xr1, wr0, wr1;

    // load tile (kc) into regs
    auto LOADT = [&](int kc) {
        xr0 = *reinterpret_cast<const float4*>(
            x + (size_t)(tok0 + r0) * D + kc + 4 * cc);
        xr1 = *reinterpret_cast<const float4*>(
            x + (size_t)(tok0 + r0 + 32) * D + kc + 4 * cc);
        const float4* src = reinterpret_cast<const float4*>(WT + (size_t)kc * 64);
        wr0 = src[tid];
        wr1 = src[tid + 512];
    };
    // write staged regs to LDS
    auto WRITE_LDS = [&]() {
        XT[(4 * cc + 0) * 65 + r0] = xr0.x;
        XT[(4 * cc + 1) * 65 + r0] = xr0.y;
        XT[(4 * cc + 2) * 65 + r0] = xr0.z;
        XT[(4 * cc + 3) * 65 + r0] = xr0.w;
        XT[(4 * cc + 0) * 65 + r0 + 32] = xr1.x;
        XT[(4 * cc + 1) * 65 + r0 + 32] = xr1.y;
        XT[(4 * cc + 2) * 65 + r0 + 32] = xr1.z;
        XT[(4 * cc + 3) * 65 + r0 + 32] = xr1.w;
        float4* dst = reinterpret_cast<float4*>(WS);
        dst[tid]       = wr0;
        dst[tid + 512] = wr1;
    };

    // prologue: stage tile 0
    LOADT(kbeg);
    WRITE_LDS();
    __syncthreads();

    for (int tile = 0; tile < NTILE; ++tile) {
        // issue next tile's global loads (latency hides under compute)
        if (tile + 1 < NTILE) LOADT(kbeg + (tile + 1) * KC);

#pragma unroll 8
        for (int k = 0; k < KC; ++k) {
            float xv = XT[k * 65 + lane];
            const float* wrow = WS + k * 64 + w * 8;   // wave-uniform
            float4 wv0 = *reinterpret_cast<const float4*>(wrow);
            float4 wv1 = *reinterpret_cast<const float4*>(wrow + 4);
            acc[0] = fmaf(xv, wv0.x, acc[0]);
            acc[1] = fmaf(xv, wv0.y, acc[1]);
            acc[2] = fmaf(xv, wv0.z, acc[2]);
            acc[3] = fmaf(xv, wv0.w, acc[3]);
            acc[4] = fmaf(xv, wv1.x, acc[4]);
            acc[5] = fmaf(xv, wv1.y, acc[5]);
            acc[6] = fmaf(xv, wv1.z, acc[6]);
            acc[7] = fmaf(xv, wv1.w, acc[7]);
        }

        if (tile + 1 < NTILE) {
            __syncthreads();              // all waves done reading this tile
            WRITE_LDS();                  // loads already landed
            __syncthreads();
        }
    }

    // transpose via LDS (reuse XT as LT[t][e], stride 65), coalesced store
    __syncthreads();
#pragma unroll
    for (int j = 0; j < 8; ++j) XT[lane * 65 + w * 8 + j] = acc[j];
    __syncthreads();
    float* out = partial + (size_t)kh * T * 64;
    for (int it = 0; it < 8; ++it) {
        int i = it * 512 + tid;           // 0..4095
        int t = i >> 6, e = i & 63;
        out[(size_t)(tok0 + t) * 64 + e] = XT[t * 65 + e];
    }
}

// --- Kernel B: combine (p0+p1)+bias, numpy f32 softmax, per-token top-k -----
__global__ __launch_bounds__(THREADS)
void softmax_topk_kernel(const float* __restrict__ part0,
                         const float* __restrict__ part1,
                         const float* __restrict__ bias,
                         float* __restrict__ logits_out,
                         float* __restrict__ probs_out,
                         float* __restrict__ pf, int* __restrict__ eid,
                         const int* __restrict__ kptr, int T, int E)
{
    const int lane = threadIdx.x & 63;
    const int wid = threadIdx.x >> 6;
    int token = blockIdx.x * 4 + wid;
    if (token >= T) token = T - 1;

    int k = *kptr;
    if (k > E) k = E;
    if (k > KMAX) k = KMAX;

    size_t idx = (size_t)token * 64 + lane;
    // z = (c1 + c2) + b  -- exact reference panel-fold order
    float z = (part0[idx] + part1[idx]) + bias[lane];
    logits_out[idx] = z;

    float m = z;
#pragma unroll
    for (int d = 1; d < 64; d <<= 1) m = fmaxf(m, __shfl_xor(m, d));

    float e32 = np_expf_avx512(z - m);

    __shared__ float sh[4][64];
    sh[wid][lane] = e32;
    __syncthreads();

    // numpy FLOAT_pairwise_sum, baseline npyv (SSE, 4 lanes), n=64:
    // R_j[l] = e[4j+l] + e[32+4j+l]; lanewise tree; SSE3 hadd horizontal.
    const float* row = sh[wid];
    float s[4];
#pragma unroll
    for (int l = 0; l < 4; ++l) {
        float R0 = row[ 0 + l] + row[32 + l];
        float R1 = row[ 4 + l] + row[36 + l];
        float R2 = row[ 8 + l] + row[40 + l];
        float R3 = row[12 + l] + row[44 + l];
        float R4 = row[16 + l] + row[48 + l];
        float R5 = row[20 + l] + row[52 + l];
        float R6 = row[24 + l] + row[56 + l];
        float R7 = row[28 + l] + row[60 + l];
        s[l] = ((R0 + R1) + (R2 + R3)) + ((R4 + R5) + (R6 + R7));
    }
    float S = (s[0] + s[1]) + (s[2] + s[3]);   // SSE3 hadd horizontal order

    float p = e32 / S;                    // CR f32 divide
    probs_out[idx] = p;

    // per-token top-k on f32 p, tie -> lower expert id
    float pv = p;
    for (int j = 0; j < k; ++j) {
        float bp = pv;
        int be = lane;
#pragma unroll
        for (int d = 1; d < 64; d <<= 1) {
            float op = __shfl_xor(bp, d);
            int oe = __shfl_xor(be, d);
            if (op > bp || (op == bp && oe < be)) { bp = op; be = oe; }
        }
        if (lane == 0) {
            int slot = token * k + j;
            pf[slot] = bp;
            eid[slot] = be;
        }
        if (lane == be) pv = -1.0f;
    }
}

// ---------------- Kernel C: per-expert gather + bitonic sort ----------------
// Key = (f32 prob bits << 32) | (0xFFFFFFFF - slot); descending u64 sort
// == prob desc, tie -> lower slot. 1024 thr, int4 eid scan.
#define MAXN 4096
__global__ __launch_bounds__(TSORT)
void expert_sort_kernel(const float* __restrict__ pf, const int* __restrict__ eid,
                        const int* __restrict__ kptr,
                        float* __restrict__ out_probs, float* __restrict__ out_idx,
                        int T, int E, int C)
{
    __shared__ unsigned long long keys[MAXN];
    __shared__ int cnt;
    const int e = blockIdx.x;
    const int tid = threadIdx.x;
    if (tid == 0) cnt = 0;
    __syncthreads();

    int k = *kptr;
    if (k > E) k = E;
    if (k > KMAX) k = KMAX;
    const int nslots = T * k;

    // vectorized scan: int4 loads (nslots % 4 == 0 for T mult of 64)
    const int4* eid4 = reinterpret_cast<const int4*>(eid);
    const int nvec = nslots >> 2;
    for (int v = tid; v < nvec; v += TSORT) {
        int4 e4 = eid4[v];
        int sbase = v << 2;
        if (e4.x == e) {
            int pos = atomicAdd(&cnt, 1);
            if (pos < MAXN) keys[pos] =
                ((unsigned long long)__float_as_uint(pf[sbase + 0]) << 32)
              | (unsigned long long)(0xFFFFFFFFu - (unsigned)(sbase + 0));
        }
        if (e4.y == e) {
            int pos = atomicAdd(&cnt, 1);
            if (pos < MAXN) keys[pos] =
                ((unsigned long long)__float_as_uint(pf[sbase + 1]) << 32)
              | (unsigned long long)(0xFFFFFFFFu - (unsigned)(sbase + 1));
        }
        if (e4.z == e) {
            int pos = atomicAdd(&cnt, 1);
            if (pos < MAXN) keys[pos] =
                ((unsigned long long)__float_as_uint(pf[sbase + 2]) << 32)
              | (unsigned long long)(0xFFFFFFFFu - (unsigned)(sbase + 2));
        }
        if (e4.w == e) {
            int pos = atomicAdd(&cnt, 1);
            if (pos < MAXN) keys[pos] =
                ((unsigned long long)__float_as_uint(pf[sbase + 3]) << 32)
              | (unsigned long long)(0xFFFFFFFFu - (unsigned)(sbase + 3));
        }
    }
    __syncthreads();

    int n = cnt;
    if (n > MAXN) n = MAXN;

    int P = 1;
    while (P < n) P <<= 1;
    for (int i = n + tid; i < P; i += TSORT) keys[i] = 0ULL;
    __syncthreads();

    for (int size = 2; size <= P; size <<= 1) {
        for (int stride = size >> 1; stride > 0; stride >>= 1) {
            for (int i = tid; i < P; i += TSORT) {
                int j = i ^ stride;
                if (j > i) {
                    unsigned long long a = keys[i], bkey = keys[j];
                    bool up = ((i & size) == 0);
                    bool doswap = up ? (a < bkey) : (a > bkey);
                    if (doswap) { keys[i] = bkey; keys[j] = a; }
                }
            }
            __syncthreads();
        }
    }

    for (int c = tid; c < C; c += TSORT) {
        float prob, idxv;
        if (c < n) {
            unsigned long long kk = keys[c];
            prob = __uint_as_float((unsigned)(kk >> 32));
            unsigned slot = 0xFFFFFFFFu - (unsigned)(kk & 0xFFFFFFFFull);
            idxv = (float)(slot / (unsigned)k);
        } else {
            prob = 0.0f;
            idxv = -1.0f;
        }
        out_probs[(size_t)e * C + c] = prob;
        out_idx[(size_t)e * C + c] = idxv;
    }
}

extern "C" void kernel_launch(void* const* d_in, const int* in_sizes, int n_in,
                              void* d_out, int out_size, void* d_ws, size_t ws_size,
                              hipStream_t stream)
{
    const float* x   = (const float*)d_in[0];
    const float* W   = (const float*)d_in[1];
    const float* b   = (const float*)d_in[2];
    const int* kptr  = (const int*)d_in[3];

    const int E = in_sizes[2];            // 64
    const int D = in_sizes[1] / E;        // 1024
    const int T = in_sizes[0] / D;        // 32768
    const int C = (out_size - 2 * T * E) / (2 * E);   // 1280

    float* out_logits = (float*)d_out;
    float* out_probs  = out_logits + (size_t)T * E;
    float* out_eprobs = out_probs  + (size_t)T * E;
    float* out_eidx   = out_eprobs + (size_t)E * C;

    // workspace: WT (D*E f32) | pf (T*KMAX f32) | eid (T*KMAX i32) | partial
    float* WT  = (float*)d_ws;
    float* pf  = (float*)((char*)d_ws + (size_t)D * E * sizeof(float));
    int*   eid = (int*)((char*)pf + (size_t)T * KMAX * sizeof(float));
    float* partial = (float*)((char*)eid + (size_t)T * KMAX * sizeof(int));

    transpose_w_kernel<<<E, 256, 0, stream>>>(W, WT, D, E);
    gemm_partial_kernel<<<(T / 64) * 2, 512, 0, stream>>>(
        x, WT, partial, T, D, E);
    softmax_topk_kernel<<<(T + 3) / 4, THREADS, 0, stream>>>(
        partial, partial + (size_t)T * 64, b, out_logits, out_probs,
        pf, eid, kptr, T, E);
    expert_sort_kernel<<<E, TSORT, 0, stream>>>(
        pf, eid, kptr, out_eprobs, out_eidx, T, E, C);
}

// Round 26
// 133.816 us; speedup vs baseline: 3.7339x; 1.2093x over previous
//
#include <hip/hip_runtime.h>
#include <stdint.h>

// TopKRouter: T=32768, D=1024, E=64, k=2 (device scalar), C=1280 (from out_size).
//
// Correctness model (VERIFIED PASSING r19-r25): np golden = numpy f32
// transliteration.
// logits = x @ W.T + b, K panels [0,512)[512,1024): single-accumulator
//   ascending-k f32 FMA chain per panel, panels summed left-to-right, + b:
//   z = (c1 + c2) + b. softmax f32: AVX512 FLOAT_exp (Cephes, FMA, rint,
//   scalef); SSE npyv 4-lane pairwise sum + SSE3 hadd horizontal; CR divide;
//   exact max-subtract. top-k & capacity sort: ties -> lower index (stable).
// expert_indices stored as f32 values (-1.0f padding).
//
// r26: W reads moved off the LDS pipe. r25 was LDS-issue-bound (~2.5x over:
// 2 wave-uniform ds_read_b128 + 1 ds_read_b32 per 16 VALU-cyc, x4 SIMDs
// sharing one LDS unit; VALUBusy 35%). W offset is wave-uniform ->
// readfirstlane to SGPR -> scalar loads (s_load_dwordx8 path, scalar cache
// broadcast). WS LDS staging deleted (LDS 33->17KB). W bits + chain order
// untouched (bit-exact).

#define THREADS 256
#define TSORT 1024
#define KMAX 16

// ---- numpy AVX512 FLOAT_exp replica: Cephes constants, FMA, rint quadrant ---
__device__ __forceinline__ float np_expf_avx512(float x)
{
    const float log2e = 1.442695040888963f;      // NPY_LOG2Ef
    float t = x * log2e;                          // separate mul (vmulps)
    float q = rintf(t);                           // roundscale nearest-even
    float r = fmaf(q, -0.693359375f, x);          // Cody-Waite hi (fma)
    r = fmaf(q, 2.12194440e-4f, r);               // Cody-Waite lo (fma)
    float y = 1.9875691500E-4f;                   // cephes_exp_p0..p5
    y = fmaf(y, r, 1.3981999507E-3f);
    y = fmaf(y, r, 8.3334519073E-3f);
    y = fmaf(y, r, 4.1665795894E-2f);
    y = fmaf(y, r, 1.6666665459E-1f);
    y = fmaf(y, r, 5.0000001201E-1f);
    float rr = r * r;                             // separate mul
    y = fmaf(y, rr, r);                           // poly*r^2 + r
    y = y + 1.0f;
    return ldexpf(y, (int)q);                     // vscalefps (q integral)
}

// ---------------- Kernel T: transpose W (E x D) -> WT (D x E, k-major) -------
__global__ __launch_bounds__(256)
void transpose_w_kernel(const float* __restrict__ W, float* __restrict__ WT,
                        int D, int E)
{
    const int e = blockIdx.x;
    for (int k = threadIdx.x; k < D; k += 256)
        WT[(size_t)k * E + e] = W[(size_t)e * D + k];
}

// ------- Kernel A: f32 partial logits, one 512-wide K-panel chain per block --
// Grid: (T/64)*2 blocks x 512 thr (8 waves). kh = blockIdx.x & 1 selects the
// K panel; tile = blockIdx.x >> 1 selects 64 tokens. lane = token; wave w =
// experts [8w, 8w+8). Per thread: acc[8] f32 chains (ascending k, serial).
// x staged in LDS (transposed, stride 65, conflict-free, async-stage split);
// W read via wave-uniform SCALAR loads (readfirstlane offset -> SGPR).
#define KC 64
#define NTILE 8                       // 512 / KC
__global__ __launch_bounds__(512, 8)
void gemm_partial_kernel(const float* __restrict__ x, const float* __restrict__ WT,
                         float* __restrict__ partial, int T, int D, int E)
{
    const int tid  = threadIdx.x;
    const int lane = tid & 63;
    const int w    = tid >> 6;            // 0..7: expert octet
    const int kh   = blockIdx.x & 1;      // K panel
    const int tok0 = (blockIdx.x >> 1) * 64;
    const int kbeg = kh * 512;
    // wave-uniform expert-octet offset, hoisted to SGPR
    const int wbase = __builtin_amdgcn_readfirstlane(w * 8);

    __shared__ float XT[64 * 65];         // XT[k][t] stride 65; reused as LT

    float acc[8];
#pragma unroll
    for (int j = 0; j < 8; ++j) acc[j] = 0.0f;

    const int cc = tid & 15;              // float4 index within a 64-float row
    const int r0 = tid >> 4;              // 0..31 (two x rows: r0, r0+32)

    float4 xr0, xr1;
    auto LOADX = [&](int kc) {
        xr0 = *reinterpret_cast<const float4*>(
            x + (size_t)(tok0 + r0) * D + kc + 4 * cc);
        xr1 = *reinterpret_cast<const float4*>(
            x + (size_t)(tok0 + r0 + 32) * D + kc + 4 * cc);
    };
    auto WRITE_LDS = [&]() {
        XT[(4 * cc + 0) * 65 + r0] = xr0.x;
        XT[(4 * cc + 1) * 65 + r0] = xr0.y;
        XT[(4 * cc + 2) * 65 + r0] = xr0.z;
        XT[(4 * cc + 3) * 65 + r0] = xr0.w;
        XT[(4 * cc + 0) * 65 + r0 + 32] = xr1.x;
        XT[(4 * cc + 1) * 65 + r0 + 32] = xr1.y;
        XT[(4 * cc + 2) * 65 + r0 + 32] = xr1.z;
        XT[(4 * cc + 3) * 65 + r0 + 32] = xr1.w;
    };

    // prologue: stage x tile 0
    LOADX(kbeg);
    WRITE_LDS();
    __syncthreads();

    for (int tile = 0; tile < NTILE; ++tile) {
        // issue next tile's x loads (latency hides under compute)
        if (tile + 1 < NTILE) LOADX(kbeg + (tile + 1) * KC);

        // wave-uniform W panel base for this tile (SGPR arithmetic)
        const float* wpanel = WT + (size_t)(kbeg + tile * KC) * 64 + wbase;

#pragma unroll 8
        for (int k = 0; k < KC; ++k) {
            float xv = XT[k * 65 + lane];
            const float* wp = wpanel + k * 64;   // uniform -> scalar loads
            float w0 = wp[0], w1 = wp[1], w2 = wp[2], w3 = wp[3];
            float w4 = wp[4], w5 = wp[5], w6 = wp[6], w7 = wp[7];
            acc[0] = fmaf(xv, w0, acc[0]);
            acc[1] = fmaf(xv, w1, acc[1]);
            acc[2] = fmaf(xv, w2, acc[2]);
            acc[3] = fmaf(xv, w3, acc[3]);
            acc[4] = fmaf(xv, w4, acc[4]);
            acc[5] = fmaf(xv, w5, acc[5]);
            acc[6] = fmaf(xv, w6, acc[6]);
            acc[7] = fmaf(xv, w7, acc[7]);
        }

        if (tile + 1 < NTILE) {
            __syncthreads();              // all waves done reading this tile
            WRITE_LDS();                  // loads already landed
            __syncthreads();
        }
    }

    // transpose via LDS (reuse XT as LT[t][e], stride 65), coalesced store
    __syncthreads();
#pragma unroll
    for (int j = 0; j < 8; ++j) XT[lane * 65 + w * 8 + j] = acc[j];
    __syncthreads();
    float* out = partial + (size_t)kh * T * 64;
    for (int it = 0; it < 8; ++it) {
        int i = it * 512 + tid;           // 0..4095
        int t = i >> 6, e = i & 63;
        out[(size_t)(tok0 + t) * 64 + e] = XT[t * 65 + e];
    }
}

// --- Kernel B: combine (p0+p1)+bias, numpy f32 softmax, per-token top-k -----
__global__ __launch_bounds__(THREADS)
void softmax_topk_kernel(const float* __restrict__ part0,
                         const float* __restrict__ part1,
                         const float* __restrict__ bias,
                         float* __restrict__ logits_out,
                         float* __restrict__ probs_out,
                         float* __restrict__ pf, int* __restrict__ eid,
                         const int* __restrict__ kptr, int T, int E)
{
    const int lane = threadIdx.x & 63;
    const int wid = threadIdx.x >> 6;
    int token = blockIdx.x * 4 + wid;
    if (token >= T) token = T - 1;

    int k = *kptr;
    if (k > E) k = E;
    if (k > KMAX) k = KMAX;

    size_t idx = (size_t)token * 64 + lane;
    // z = (c1 + c2) + b  -- exact reference panel-fold order
    float z = (part0[idx] + part1[idx]) + bias[lane];
    logits_out[idx] = z;

    float m = z;
#pragma unroll
    for (int d = 1; d < 64; d <<= 1) m = fmaxf(m, __shfl_xor(m, d));

    float e32 = np_expf_avx512(z - m);

    __shared__ float sh[4][64];
    sh[wid][lane] = e32;
    __syncthreads();

    // numpy FLOAT_pairwise_sum, baseline npyv (SSE, 4 lanes), n=64:
    // R_j[l] = e[4j+l] + e[32+4j+l]; lanewise tree; SSE3 hadd horizontal.
    const float* row = sh[wid];
    float s[4];
#pragma unroll
    for (int l = 0; l < 4; ++l) {
        float R0 = row[ 0 + l] + row[32 + l];
        float R1 = row[ 4 + l] + row[36 + l];
        float R2 = row[ 8 + l] + row[40 + l];
        float R3 = row[12 + l] + row[44 + l];
        float R4 = row[16 + l] + row[48 + l];
        float R5 = row[20 + l] + row[52 + l];
        float R6 = row[24 + l] + row[56 + l];
        float R7 = row[28 + l] + row[60 + l];
        s[l] = ((R0 + R1) + (R2 + R3)) + ((R4 + R5) + (R6 + R7));
    }
    float S = (s[0] + s[1]) + (s[2] + s[3]);   // SSE3 hadd horizontal order

    float p = e32 / S;                    // CR f32 divide
    probs_out[idx] = p;

    // per-token top-k on f32 p, tie -> lower expert id
    float pv = p;
    for (int j = 0; j < k; ++j) {
        float bp = pv;
        int be = lane;
#pragma unroll
        for (int d = 1; d < 64; d <<= 1) {
            float op = __shfl_xor(bp, d);
            int oe = __shfl_xor(be, d);
            if (op > bp || (op == bp && oe < be)) { bp = op; be = oe; }
        }
        if (lane == 0) {
            int slot = token * k + j;
            pf[slot] = bp;
            eid[slot] = be;
        }
        if (lane == be) pv = -1.0f;
    }
}

// ---------------- Kernel C: per-expert gather + bitonic sort ----------------
// Key = (f32 prob bits << 32) | (0xFFFFFFFF - slot); descending u64 sort
// == prob desc, tie -> lower slot. 1024 thr, int4 eid scan.
#define MAXN 4096
__global__ __launch_bounds__(TSORT)
void expert_sort_kernel(const float* __restrict__ pf, const int* __restrict__ eid,
                        const int* __restrict__ kptr,
                        float* __restrict__ out_probs, float* __restrict__ out_idx,
                        int T, int E, int C)
{
    __shared__ unsigned long long keys[MAXN];
    __shared__ int cnt;
    const int e = blockIdx.x;
    const int tid = threadIdx.x;
    if (tid == 0) cnt = 0;
    __syncthreads();

    int k = *kptr;
    if (k > E) k = E;
    if (k > KMAX) k = KMAX;
    const int nslots = T * k;

    // vectorized scan: int4 loads (nslots % 4 == 0 for T mult of 64)
    const int4* eid4 = reinterpret_cast<const int4*>(eid);
    const int nvec = nslots >> 2;
    for (int v = tid; v < nvec; v += TSORT) {
        int4 e4 = eid4[v];
        int sbase = v << 2;
        if (e4.x == e) {
            int pos = atomicAdd(&cnt, 1);
            if (pos < MAXN) keys[pos] =
                ((unsigned long long)__float_as_uint(pf[sbase + 0]) << 32)
              | (unsigned long long)(0xFFFFFFFFu - (unsigned)(sbase + 0));
        }
        if (e4.y == e) {
            int pos = atomicAdd(&cnt, 1);
            if (pos < MAXN) keys[pos] =
                ((unsigned long long)__float_as_uint(pf[sbase + 1]) << 32)
              | (unsigned long long)(0xFFFFFFFFu - (unsigned)(sbase + 1));
        }
        if (e4.z == e) {
            int pos = atomicAdd(&cnt, 1);
            if (pos < MAXN) keys[pos] =
                ((unsigned long long)__float_as_uint(pf[sbase + 2]) << 32)
              | (unsigned long long)(0xFFFFFFFFu - (unsigned)(sbase + 2));
        }
        if (e4.w == e) {
            int pos = atomicAdd(&cnt, 1);
            if (pos < MAXN) keys[pos] =
                ((unsigned long long)__float_as_uint(pf[sbase + 3]) << 32)
              | (unsigned long long)(0xFFFFFFFFu - (unsigned)(sbase + 3));
        }
    }
    __syncthreads();

    int n = cnt;
    if (n > MAXN) n = MAXN;

    int P = 1;
    while (P < n) P <<= 1;
    for (int i = n + tid; i < P; i += TSORT) keys[i] = 0ULL;
    __syncthreads();

    for (int size = 2; size <= P; size <<= 1) {
        for (int stride = size >> 1; stride > 0; stride >>= 1) {
            for (int i = tid; i < P; i += TSORT) {
                int j = i ^ stride;
                if (j > i) {
                    unsigned long long a = keys[i], bkey = keys[j];
                    bool up = ((i & size) == 0);
                    bool doswap = up ? (a < bkey) : (a > bkey);
                    if (doswap) { keys[i] = bkey; keys[j] = a; }
                }
            }
            __syncthreads();
        }
    }

    for (int c = tid; c < C; c += TSORT) {
        float prob, idxv;
        if (c < n) {
            unsigned long long kk = keys[c];
            prob = __uint_as_float((unsigned)(kk >> 32));
            unsigned slot = 0xFFFFFFFFu - (unsigned)(kk & 0xFFFFFFFFull);
            idxv = (float)(slot / (unsigned)k);
        } else {
            prob = 0.0f;
            idxv = -1.0f;
        }
        out_probs[(size_t)e * C + c] = prob;
        out_idx[(size_t)e * C + c] = idxv;
    }
}

extern "C" void kernel_launch(void* const* d_in, const int* in_sizes, int n_in,
                              void* d_out, int out_size, void* d_ws, size_t ws_size,
                              hipStream_t stream)
{
    const float* x   = (const float*)d_in[0];
    const float* W   = (const float*)d_in[1];
    const float* b   = (const float*)d_in[2];
    const int* kptr  = (const int*)d_in[3];

    const int E = in_sizes[2];            // 64
    const int D = in_sizes[1] / E;        // 1024
    const int T = in_sizes[0] / D;        // 32768
    const int C = (out_size - 2 * T * E) / (2 * E);   // 1280

    float* out_logits = (float*)d_out;
    float* out_probs  = out_logits + (size_t)T * E;
    float* out_eprobs = out_probs  + (size_t)T * E;
    float* out_eidx   = out_eprobs + (size_t)E * C;

    // workspace: WT (D*E f32) | pf (T*KMAX f32) | eid (T*KMAX i32) | partial
    float* WT  = (float*)d_ws;
    float* pf  = (float*)((char*)d_ws + (size_t)D * E * sizeof(float));
    int*   eid = (int*)((char*)pf + (size_t)T * KMAX * sizeof(float));
    float* partial = (float*)((char*)eid + (size_t)T * KMAX * sizeof(int));

    transpose_w_kernel<<<E, 256, 0, stream>>>(W, WT, D, E);
    gemm_partial_kernel<<<(T / 64) * 2, 512, 0, stream>>>(
        x, WT, partial, T, D, E);
    softmax_topk_kernel<<<(T + 3) / 4, THREADS, 0, stream>>>(
        partial, partial + (size_t)T * 64, b, out_logits, out_probs,
        pf, eid, kptr, T, E);
    expert_sort_kernel<<<E, TSORT, 0, stream>>>(
        pf, eid, kptr, out_eprobs, out_eidx, T, E, C);
}